// Round 6
// baseline (116.980 us; speedup 1.0000x reference)
//
#include <hip/hip_runtime.h>

#define C_     20
#define H_     64
#define W_     2048
#define HW_    (H_*W_)
#define KN     24          // 5x5 taps minus center
#define TH     8
#define TW     64
#define TR     (TH+4)      // 12
#define TC     (TW+4)      // 68
#define PLANE  (TR*TC)     // 816 spatial positions
#define DELEMS (C_*PLANE)  // 16320
#define NTHR   512
#define DSTG   32          // ceil(16320/512)
#define SCLS   21          // class stride in LDS (odd -> conflict-free banks)
#define MPAD   1024

// async global->LDS (mask only): wave-uniform LDS base, HW adds lane*4
#define GLOAD_LDS(SRC, DST)                                                     \
    __builtin_amdgcn_global_load_lds(                                           \
        (const __attribute__((address_space(1))) void*)(SRC),                   \
        (__attribute__((address_space(3))) void*)(DST), 4, 0, 0)

constexpr int KI[KN] = {0,0,0,0,0, 1,1,1,1,1, 2,2,2,2, 3,3,3,3,3, 4,4,4,4,4};
constexpr int KJ[KN] = {0,1,2,3,4, 0,1,2,3,4, 0,1,3,4, 0,1,2,3,4, 0,1,2,3,4};

// NOTE: second arg empirically caps VGPR at 256/arg on this hipcc
// (arg=4 -> 64 VGPR, observed rounds 2/3/5 -> spills). arg=2 -> 128 VGPR.
__global__ __launch_bounds__(NTHR, 2) void lp_kernel(
    const float* __restrict__ data,
    const float* __restrict__ mask,
    const float* __restrict__ bilat,
    const float* __restrict__ ang_w,
    const float* __restrict__ bi_w,
    const float* __restrict__ zbuf,
    float* __restrict__ out)
{
    __shared__ float s_data[PLANE*SCLS];   // [pos][cls], 68.5 KB, class-interleaved
    __shared__ float s_mask[MPAD];         // 4 KB

    const int tid = threadIdx.x;
    int bid = blockIdx.x;
    bid = (bid & 7)*64 + (bid >> 3);       // XCD swizzle, 512 % 8 == 0 -> bijective

    const int tx = bid & 31;               // W/TW = 32
    const int ty = (bid >> 5) & 7;         // H/TH = 8
    const int b  = bid >> 8;
    const int y0 = ty*TH, x0 = tx*TW;

    const float* dbase = data + (size_t)b*C_*HW_;
    const float* mbase = mask + (size_t)b*HW_;
    const int wbase = tid & ~63;

    const int lx  = tid & 63;
    const int lyy = tid >> 6;              // 8 waves = 8 tile rows
    const int y = y0 + lyy, x = x0 + lx;

    // bilateral per-pixel (issued first; oldest vmcnt, done long before use)
    float bb[KN];
    {
        const float* bibase = bilat + (size_t)b*KN*HW_ + (size_t)y*W_ + x;
#pragma unroll
        for (int kp = 0; kp < KN; ++kp) bb[kp] = bibase[(size_t)kp*HW_];
    }

    // mask tile via async DMA (linear dest)
#pragma unroll
    for (int s = 0; s < MPAD/NTHR; ++s) {
        const int idx = tid + s*NTHR;
        const int r   = idx / TC;
        const int col = idx - r*TC;
        const int gy = y0 + r - 2, gx = x0 + col - 2;
        const bool ok = (idx < PLANE) & (gy >= 0) & (gy < H_) & (gx >= 0) & (gx < W_);
        const float* src = ok ? (mbase + (gy*W_ + gx)) : zbuf;
        GLOAD_LDS(src, s_mask + s*NTHR + wbase);
    }

    // data tile: coalesced plane-linear global reads -> scatter write [pos*21+cls]
#pragma unroll
    for (int s = 0; s < DSTG; ++s) {
        const int g = tid + s*NTHR;        // linear over (cls, pos), pos fastest
        if (g < DELEMS) {
            const int cls = g / PLANE;
            const int pos = g - cls*PLANE;
            const int r   = pos / TC;
            const int col = pos - r*TC;
            const int gy = y0 + r - 2, gx = x0 + col - 2;
            const bool ok = (gy >= 0) & (gy < H_) & (gx >= 0) & (gx < W_);
            const float* src = ok ? (dbase + (size_t)cls*HW_ + (gy*W_ + gx)) : dbase;
            float v = *src;
            s_data[pos*SCLS + cls] = ok ? v : 0.0f;
        }
    }
    __syncthreads();   // drains mask DMA (vmcnt) + data ds_writes (lgkm)

    float a[C_], ba[C_], bi[C_];
#pragma unroll
    for (int c = 0; c < C_; ++c) { a[c] = 0.0f; ba[c] = 0.0f; bi[c] = 0.0f; }

    const float* sbase = s_data + (lyy*TC + lx)*SCLS;
    const int    mbase_l = lyy*TC + lx;

    // k-outer: one tap -> 20 consecutive LDS words (10 ds_read2, conflict-free)
    // feeding 80 FMAs. flat = k*20+cls is compile-time -> bi[] static-indexed.
#pragma unroll
    for (int k = 0; k < KN; ++k) {
        const int i = KI[k], j = KJ[k];
        const float mm_k = s_mask[mbase_l + i*TC + j];
        const float* p = sbase + (i*TC + j)*SCLS;
        float v[C_];
#pragma unroll
        for (int c = 0; c < C_; ++c) v[c] = p[c];
#pragma unroll
        for (int c = 0; c < C_; ++c) {
            a[c]  = fmaf(ang_w[c*25 + i*5 + j], v[c], a[c]);   // uniform -> s_load
            ba[c] = fmaf(bi_w [c*25 + i*5 + j], v[c], ba[c]);
            const int flat = k*C_ + c;                          // torch .view remap
            bi[flat/KN] = fmaf(bb[flat%KN], v[c]*mm_k, bi[flat/KN]);
        }
    }

    const float m_c = s_mask[mbase_l + 2*TC + 2];

    float* aout = out + ((size_t)b*C_*H_ + y)*W_ + x;
    float* bout = aout + (size_t)2*C_*HW_;

#pragma unroll
    for (int c = 0; c < C_; ++c) {
        aout[(size_t)c*HW_] = a[c];
        bout[(size_t)c*HW_] = m_c * ba[c] * bi[c];
    }
}

extern "C" void kernel_launch(void* const* d_in, const int* in_sizes, int n_in,
                              void* d_out, int out_size, void* d_ws, size_t ws_size,
                              hipStream_t stream) {
    const float* data  = (const float*)d_in[0];
    const float* mask  = (const float*)d_in[1];
    const float* bilat = (const float*)d_in[2];
    const float* ang_w = (const float*)d_in[3];
    const float* bi_w  = (const float*)d_in[4];
    float* out = (float*)d_out;

    hipMemsetAsync(d_ws, 0, 256, stream);   // zero word for OOB mask-halo lanes

    const int nblocks = 2 * (H_/TH) * (W_/TW);  // 512
    lp_kernel<<<nblocks, NTHR, 0, stream>>>(data, mask, bilat, ang_w, bi_w,
                                            (const float*)d_ws, out);
}

// Round 7
// 33.813 us; speedup vs baseline: 3.4596x; 3.4596x over previous
//
#include <hip/hip_runtime.h>

#define C_     20
#define H_     64
#define W_     2048
#define HW_    (H_*W_)
#define KN     24          // 5x5 taps minus center
#define TH     8
#define TW     64
#define TR     (TH+4)      // 12
#define TC     (TW+4)      // 68
#define PLANE  (TR*TC)     // 816 spatial positions per class plane
#define NTHR   512
#define NCH    10          // classes per chunk
#define CHELE  (NCH*PLANE) // 8160
#define CHPAD  8192        // 16*512 (tail 32 slots dead pad)
#define CSTG   (CHPAD/NTHR)// 16

// async global->LDS: wave-uniform LDS base, HW adds lane*4; per-lane global src
#define GLOAD_LDS(SRC, DST)                                                     \
    __builtin_amdgcn_global_load_lds(                                           \
        (const __attribute__((address_space(1))) void*)(SRC),                   \
        (__attribute__((address_space(3))) void*)(DST), 4, 0, 0)

constexpr int KI[KN] = {0,0,0,0,0, 1,1,1,1,1, 2,2,2,2, 3,3,3,3,3, 4,4,4,4,4};
constexpr int KJ[KN] = {0,1,2,3,4, 0,1,2,3,4, 0,1,3,4, 0,1,2,3,4, 0,1,2,3,4};

__shared__ float s_data[2*CHPAD];  // fwd decl trick not needed; defined in kernel

template<int CHUNK>
__device__ __forceinline__ void compute_chunk(
    const float* __restrict__ sbuf, int lyy, int lx,
    const float* __restrict__ ang_w, const float* __restrict__ bi_w,
    const float (&bb)[KN], const float (&mm)[KN],
    float (&bi)[C_], float (&biang)[C_], float* __restrict__ aout)
{
#pragma unroll
    for (int cl = 0; cl < NCH; ++cl) {
        const int cls = CHUNK*NCH + cl;
        float a = 0.0f, ba = 0.0f;
        const float* srow = sbuf + cl*PLANE + lyy*TC + lx;
#pragma unroll
        for (int k = 0; k < KN; ++k) {
            const int i = KI[k], j = KJ[k];
            const float v = srow[i*TC + j];          // pairs merge to ds_read2_b32
            a  += ang_w[cls*25 + i*5 + j] * v;       // wave-uniform -> s_load
            ba += bi_w [cls*25 + i*5 + j] * v;
            const int flat = k*C_ + cls;             // torch .view remap (k,cls)->(c',k')
            bi[flat/KN] += bb[flat%KN] * (v * mm[k]);
        }
        aout[(size_t)cls*HW_] = a;                   // fire-and-forget store
        biang[cls] = ba;
    }
}

__global__ __launch_bounds__(NTHR, 4) void lp_kernel(
    const float* __restrict__ data,
    const float* __restrict__ mask,
    const float* __restrict__ bilat,
    const float* __restrict__ ang_w,
    const float* __restrict__ bi_w,
    const float* __restrict__ zbuf,
    float* __restrict__ out)
{
    __shared__ float s_buf[2*CHPAD];   // 64 KB: two 10-class chunk buffers
    __shared__ float s_mask[1024];     // 4 KB

    const int tid = threadIdx.x;
    int bid = blockIdx.x;
    bid = (bid & 7)*64 + (bid >> 3);     // XCD swizzle, 512 % 8 == 0 -> bijective

    const int tx = bid & 31;             // W/TW = 32
    const int ty = (bid >> 5) & 7;       // H/TH = 8
    const int b  = bid >> 8;
    const int y0 = ty*TH, x0 = tx*TW;

    const float* dbase = data + (size_t)b*C_*HW_;
    const float* mbase = mask + (size_t)b*HW_;
    const int wbase = tid & ~63;         // wave-uniform lane-0 slot

    // DMA one 10-class chunk into buffer BUF (registers untouched -> no spill risk)
    #define STAGE(CHUNK, BUF) do {                                                   \
        _Pragma("unroll")                                                            \
        for (int s = 0; s < CSTG; ++s) {                                             \
            const int idx = tid + s*NTHR;                                            \
            const int c   = idx / PLANE;                                             \
            const int rem = idx - c*PLANE;                                           \
            const int r   = rem / TC;                                                \
            const int col = rem - r*TC;                                              \
            const int gy = y0 + r - 2, gx = x0 + col - 2;                            \
            const bool ok = (idx < CHELE) & (gy >= 0) & (gy < H_) &                  \
                            (gx >= 0) & (gx < W_);                                   \
            const float* src = ok                                                    \
                ? (dbase + (size_t)((CHUNK)*NCH + c)*HW_ + (gy*W_ + gx)) : zbuf;     \
            GLOAD_LDS(src, s_buf + (BUF)*CHPAD + s*NTHR + wbase);                    \
        }                                                                            \
    } while (0)

    // ---- phase 0: DMA chunk0 + mask, overlap bilateral register loads ----
    STAGE(0, 0);
#pragma unroll
    for (int s = 0; s < 2; ++s) {        // mask tile (816 of 1024 slots)
        const int idx = tid + s*NTHR;
        const int r   = idx / TC;
        const int col = idx - r*TC;
        const int gy = y0 + r - 2, gx = x0 + col - 2;
        const bool ok = (idx < PLANE) & (gy >= 0) & (gy < H_) & (gx >= 0) & (gx < W_);
        const float* src = ok ? (mbase + (gy*W_ + gx)) : zbuf;
        GLOAD_LDS(src, s_mask + s*NTHR + wbase);
    }

    const int lx  = tid & 63;
    const int lyy = tid >> 6;            // 8 waves = 8 tile rows
    const int y = y0 + lyy, x = x0 + lx;

    float bb[KN];
    {
        const float* bibase = bilat + (size_t)b*KN*HW_ + (size_t)y*W_ + x;
#pragma unroll
        for (int kp = 0; kp < KN; ++kp) bb[kp] = bibase[(size_t)kp*HW_];
    }

    __syncthreads();   // drains chunk0 DMA + mask DMA + bb loads

    // ---- phase 1: issue chunk1 DMA (hides under chunk0 compute) ----
    STAGE(1, 1);

    float mm[KN];
#pragma unroll
    for (int k = 0; k < KN; ++k) mm[k] = s_mask[(lyy + KI[k])*TC + (lx + KJ[k])];
    const float m_c = s_mask[(lyy + 2)*TC + (lx + 2)];

    float bi[C_], biang[C_];
#pragma unroll
    for (int c = 0; c < C_; ++c) { bi[c] = 0.0f; }

    float* aout = out + ((size_t)b*C_*H_ + y)*W_ + x;
    float* bout = aout + (size_t)2*C_*HW_;

    compute_chunk<0>(s_buf,         lyy, lx, ang_w, bi_w, bb, mm, bi, biang, aout);

    __syncthreads();   // drains chunk1 DMA; chunk0 reads done

    compute_chunk<1>(s_buf + CHPAD, lyy, lx, ang_w, bi_w, bb, mm, bi, biang, aout);

#pragma unroll
    for (int c = 0; c < C_; ++c)
        bout[(size_t)c*HW_] = m_c * biang[c] * bi[c];

    #undef STAGE
}

extern "C" void kernel_launch(void* const* d_in, const int* in_sizes, int n_in,
                              void* d_out, int out_size, void* d_ws, size_t ws_size,
                              hipStream_t stream) {
    const float* data  = (const float*)d_in[0];
    const float* mask  = (const float*)d_in[1];
    const float* bilat = (const float*)d_in[2];
    const float* ang_w = (const float*)d_in[3];
    const float* bi_w  = (const float*)d_in[4];
    float* out = (float*)d_out;

    hipMemsetAsync(d_ws, 0, 256, stream);   // zero word for OOB halo lanes

    const int nblocks = 2 * (H_/TH) * (W_/TW);  // 512
    lp_kernel<<<nblocks, NTHR, 0, stream>>>(data, mask, bilat, ang_w, bi_w,
                                            (const float*)d_ws, out);
}